// Round 15
// baseline (373.243 us; speedup 1.0000x reference)
//
#include <hip/hip_runtime.h>
#include <hip/hip_bf16.h>
#include <cstddef>

typedef __attribute__((ext_vector_type(8))) short short8;
typedef __attribute__((ext_vector_type(4))) float f32x4;

constexpr int CB = 2048;   // batch
constexpr int CD = 512;    // input dim
constexpr int CH = 2048;   // expert hidden
constexpr int CO = 512;    // output dim
constexpr int CE = 8;      // experts
constexpr int CR = 4;      // regimes
constexpr int MBY = 5;     // M-tile slots per regime (Mg <= 640 guarded by m0>=Mg exit)

// ---------- helpers ----------
__device__ __forceinline__ float bs2f(short s){
  union { float f; unsigned u; } u; u.u = ((unsigned)(unsigned short)s) << 16; return u.f;
}
__device__ __forceinline__ short f2bs(float x){
  union { __hip_bfloat16 h; short s; } u; u.h = __float2bfloat16(x); return u.s;
}

#define GLL(g, l) __builtin_amdgcn_global_load_lds((const __attribute__((address_space(1))) void*)(g), (__attribute__((address_space(3))) void*)(l), 16, 0, 0)

__device__ __forceinline__ short8 ln8(short8 raw, float mean, float rstd,
                                      float4 g01, float4 g23, float4 b01, float4 b23){
  const float g[8] = {g01.x,g01.y,g01.z,g01.w,g23.x,g23.y,g23.z,g23.w};
  const float b[8] = {b01.x,b01.y,b01.z,b01.w,b23.x,b23.y,b23.z,b23.w};
  short8 o;
#pragma unroll
  for (int j = 0; j < 8; j++){
    const float v = (bs2f(raw[j]) - mean) * rstd * g[j] + b[j];
    o[j] = f2bs(fmaxf(v, 0.f));
  }
  return o;
}

__device__ __forceinline__ void block_reduce2(float& a, float& b){
#pragma unroll
  for (int off = 32; off; off >>= 1){ a += __shfl_xor(a, off, 64); b += __shfl_xor(b, off, 64); }
  __shared__ float sa[4], sb[4];
  const int wid = threadIdx.x >> 6, lane = threadIdx.x & 63;
  __syncthreads();
  if (lane == 0){ sa[wid] = a; sb[wid] = b; }
  __syncthreads();
  a = sa[0] + sa[1] + sa[2] + sa[3];
  b = sb[0] + sb[1] + sb[2] + sb[3];
}

// ---------- regime bucketing: count + scan + scatter in ONE single-block launch ----------
__global__ __launch_bounds__(1024) void k_bucket(const int* __restrict__ regime,
                                                 int* __restrict__ meta, int* __restrict__ perm){
  __shared__ int cnt[4], cur[4];
  const int t = threadIdx.x;
  if (t < 4) cnt[t] = 0;
  __syncthreads();
  const int r0 = regime[t];
  const int r1 = regime[t + 1024];
  atomicAdd(&cnt[r0], 1);
  atomicAdd(&cnt[r1], 1);
  __syncthreads();
  if (t == 0){
    const int c0 = cnt[0], c1 = cnt[1], c2 = cnt[2], c3 = cnt[3];
    meta[0] = 0; meta[1] = c0; meta[2] = c0 + c1; meta[3] = c0 + c1 + c2; meta[4] = c0 + c1 + c2 + c3;
    cur[0] = 0; cur[1] = c0; cur[2] = c0 + c1; cur[3] = c0 + c1 + c2;
  }
  __syncthreads();
  { int p = atomicAdd(&cur[r0], 1); perm[p] = t; }
  { int p = atomicAdd(&cur[r1], 1); perm[p] = t + 1024; }
}

// ---------- 64x64 f32 [K][N] -> bf16 [N][K] transpose+convert tile ----------
__device__ __forceinline__ void cvtt_tile(float (*tile)[65], const float* __restrict__ in,
                                          short* __restrict__ outp, int K, int N,
                                          int bx, int by, int bz){
  const int k0 = by * 64, n0 = bx * 64;
  const float* src = in + (size_t)bz * K * N;
  short* dst = outp + (size_t)bz * K * N;
  const int t = threadIdx.x;
  const int kk = t >> 4, nq = (t & 15) * 4;
#pragma unroll
  for (int j = 0; j < 4; j++){
    float4 v = *(const float4*)(src + (size_t)(k0 + kk + j * 16) * N + n0 + nq);
    tile[kk + j * 16][nq] = v.x; tile[kk + j * 16][nq + 1] = v.y;
    tile[kk + j * 16][nq + 2] = v.z; tile[kk + j * 16][nq + 3] = v.w;
  }
  __syncthreads();
  const int n = t >> 2, kq = (t & 3) * 16;
  short8 o0, o1;
#pragma unroll
  for (int j = 0; j < 8; j++) o0[j] = f2bs(tile[kq + j][n]);
#pragma unroll
  for (int j = 0; j < 8; j++) o1[j] = f2bs(tile[kq + 8 + j][n]);
  short* drow = dst + (size_t)(n0 + n) * K + k0 + kq;
  *(short8*)(drow) = o0;
  *(short8*)(drow + 8) = o1;
}

// ---------- prep (critical-path only): xsplit | rwt | cvt_t(ew1) ----------
__global__ __launch_bounds__(256) void k_prep(
    const float* __restrict__ x, const int* __restrict__ perm,
    short* __restrict__ xp, short* __restrict__ xd,
    const float* __restrict__ rw1, const float* __restrict__ rb1,
    short* __restrict__ wtR, float* __restrict__ rbias,
    const float* __restrict__ ew1, short* __restrict__ wt1){
  __shared__ float tile[64][65];
  const int s = blockIdx.x;
  const int t = threadIdx.x;
  if (s < 2048){
    const int i = s, b = perm[i], c = t * 2;
    float2 v = *(const float2*)(x + (size_t)b * CD + c);
    short2 hi; hi.x = f2bs(v.x); hi.y = f2bs(v.y);
    short2 lo; lo.x = f2bs(v.x - bs2f(hi.x)); lo.y = f2bs(v.y - bs2f(hi.y));
    *(short2*)(xp + (size_t)i * CD + c) = hi;
    short* row = xd + (size_t)i * 1536;
    *(short2*)(row + c) = hi;
    *(short2*)(row + 512 + c) = hi;
    *(short2*)(row + 1024 + c) = lo;
    return;
  }
  if (s < 3072){
    // rwt: router B' [r][n][1536] = [Whi | Wlo | Whi]; rbias at by==0
    const int i = s - 2048;
    const int bx = i & 31, by = (i >> 5) & 7, r = i >> 8;
    const int k0 = by * 64, n0 = bx * 64;
    const float* src = rw1 + (size_t)r * (CD + CR) * CH;
    short* dst = wtR + (size_t)r * CH * 1536;
    if (by == 0 && t < 64){
      const int n = n0 + t;
      rbias[r * CH + n] = rb1[(size_t)r * CH + n] + src[((size_t)(CD + r)) * CH + n];
    }
    const int kk = t >> 4, nq = (t & 15) * 4;
#pragma unroll
    for (int j = 0; j < 4; j++){
      float4 v = *(const float4*)(src + (size_t)(k0 + kk + j * 16) * CH + n0 + nq);
      tile[kk + j * 16][nq] = v.x; tile[kk + j * 16][nq + 1] = v.y;
      tile[kk + j * 16][nq + 2] = v.z; tile[kk + j * 16][nq + 3] = v.w;
    }
    __syncthreads();
    const int n = t >> 2, kq = (t & 3) * 16;
    short8 h0, h1, l0, l1;
#pragma unroll
    for (int j = 0; j < 8; j++){
      float f = tile[kq + j][n];
      short h = f2bs(f); h0[j] = h; l0[j] = f2bs(f - bs2f(h));
    }
#pragma unroll
    for (int j = 0; j < 8; j++){
      float f = tile[kq + 8 + j][n];
      short h = f2bs(f); h1[j] = h; l1[j] = f2bs(f - bs2f(h));
    }
    short* drow = dst + (size_t)(n0 + n) * 1536;
    *(short8*)(drow + k0 + kq) = h0;        *(short8*)(drow + k0 + kq + 8) = h1;
    *(short8*)(drow + 512 + k0 + kq) = l0;  *(short8*)(drow + 512 + k0 + kq + 8) = l1;
    *(short8*)(drow + 1024 + k0 + kq) = h0; *(short8*)(drow + 1024 + k0 + kq + 8) = h1;
    return;
  }
  {
    const int i = s - 3072;                 // ew1: [32 z][8 k][32 n]
    cvtt_tile(tile, ew1, wt1, CD, CH, i & 31, (i >> 5) & 7, i >> 8);
  }
}

// ---------- logits body: reduce 32 partials + softmax + top-2 + qrows ----------
__device__ __forceinline__ void logits_body(int blk,
    const float* __restrict__ part, const float* __restrict__ rb2,
    const int* __restrict__ meta, const int* __restrict__ perm,
    int* __restrict__ tki, float* __restrict__ tkw, int* __restrict__ qrows){
  const int wid = threadIdx.x >> 6, lane = threadIdx.x & 63;
  const int i = blk * 4 + wid;
  const int r = (i >= meta[1]) + (i >= meta[2]) + (i >= meta[3]);
  const int p0 = lane >> 3, e = lane & 7;
  float v = 0.f;
#pragma unroll
  for (int j = 0; j < 4; j++)
    v += part[((size_t)(p0 + 8 * j) * CB + i) * 8 + e];
  v += __shfl_xor(v, 8, 64);
  v += __shfl_xor(v, 16, 64);
  v += __shfl_xor(v, 32, 64);
  v += rb2[r * CE + e];
  float l8[8];
#pragma unroll
  for (int e2 = 0; e2 < 8; e2++) l8[e2] = __shfl(v, e2, 64);
  if (lane == 0){
    int i1 = 0; float m1 = l8[0];
#pragma unroll
    for (int e2 = 1; e2 < 8; e2++) if (l8[e2] > m1){ m1 = l8[e2]; i1 = e2; }
    int i2 = -1; float m2 = -1e30f;
#pragma unroll
    for (int e2 = 0; e2 < 8; e2++) if (e2 != i1 && l8[e2] > m2){ m2 = l8[e2]; i2 = e2; }
    const float e2w = __expf(m2 - m1);
    const float w1 = 1.f / (1.f + e2w);
    const int b = perm[i];
    tki[b * 2] = i1; tki[b * 2 + 1] = i2;
    tkw[b * 2] = w1; tkw[b * 2 + 1] = e2w * w1;
    qrows[b * 2] = b * CE + i1; qrows[b * 2 + 1] = b * CE + i2;
  }
}

// ---------- bf16 MFMA GEMM body, 128xNB*32 tile, BK=32, global_load_lds, 2-phase dbuf ----------
// NB = N-fragments per wave (4 -> 128-wide tile, 32 KiB LDS; 2 -> 64-wide, 24 KiB LDS).
// EPI: 1 = expert GEMM1 (+bias raw pre-LN out, LN stat partials)
//      3 = plain bf16 out (+bias); optional A row-gather via operm
//      4 = plain f32 out (+bias)
//      6 = fused router (+rbias, relu, contract with rw2 -> logit partials)
template<int EPI, int NB>
__device__ __forceinline__ void gemm_body(
    short* __restrict__ ldsb,
    int bx, int by, int bz,
    const short* __restrict__ A, long lda,
    const short* __restrict__ Wt, long ldw,
    const int* __restrict__ goff, int fixedM, int Ksub, int N,
    const float* __restrict__ bias, long bstride,
    short* __restrict__ outb, float* __restrict__ outf,
    const int* __restrict__ operm, const float* __restrict__ xtra,
    float* __restrict__ pstat){
  constexpr int BK = 32;
  constexpr int BSTR = 4096 + NB * 1024;   // shorts per buffer: A 4096 | B NB*1024

  const int z = bz;
  int g0 = 0, Mg = fixedM;
  if (goff){ const int r = (EPI == 6) ? z : (z >> 3); g0 = goff[r]; Mg = goff[r + 1] - g0; }
  const int m0 = by * 128;
  if (m0 >= Mg) return;
  const int n0 = bx * (NB * 32);
  const int e = z & 7;

  const short* Ab;
  if constexpr (EPI == 1 || EPI == 6) Ab = A + (size_t)g0 * (size_t)lda;
  else Ab = A;
  const short* Wb = Wt + (size_t)z * (size_t)N * (size_t)ldw;

  const int tid = threadIdx.x;
  const int lane = tid & 63, wid = tid >> 6;
  const int srow = lane >> 2;
  const int sc = (((lane & 3) ^ ((srow >> 1) & 3)) << 3);  // swizzled source k-chunk (shorts)

  int ar0 = m0 + wid * 32 + srow;
  int ar1 = ar0 + 16;
  if (ar0 > Mg - 1) ar0 = Mg - 1;
  if (ar1 > Mg - 1) ar1 = Mg - 1;
  if constexpr (EPI == 3){
    if (operm){ ar0 = operm[ar0]; ar1 = operm[ar1]; }
  }
  const short* ga0 = Ab + (size_t)ar0 * lda + sc;
  const short* ga1 = Ab + (size_t)ar1 * lda + sc;
  const int brow = n0 + wid * (NB * 8) + srow;   // NB=4: 32 rows/wave; NB=2: 16 rows/wave
  const short* gb0 = Wb + (size_t)brow * ldw + sc;
  const short* gb1 = gb0 + (size_t)16 * ldw;     // used only for NB==4

  const int wm = (wid >> 1) * 64, wn = (wid & 1) * (NB * 16);
  const int r16 = lane & 15, kb = lane >> 4;
  const int rsw = (r16 >> 1) & 3;

  f32x4 acc[4][NB];
#pragma unroll
  for (int a = 0; a < 4; a++)
#pragma unroll
    for (int b = 0; b < NB; b++) acc[a][b] = (f32x4){0.f, 0.f, 0.f, 0.f};

  const int NT = Ksub / BK;
  int buf = 0;

  {
    short* dA = ldsb + wid * 1024;
    short* dB = ldsb + 4096 + wid * (NB * 256);
    GLL(ga0, dA); GLL(ga1, dA + 512);
    GLL(gb0, dB);
    if constexpr (NB == 4){ GLL(gb1, dB + 512); }
  }
  __syncthreads();

  for (int t = 0; t < NT; ++t){
    if (t + 1 < NT){
      const int kof = (t + 1) * BK;
      short* dA = ldsb + (buf ^ 1) * BSTR + wid * 1024;
      short* dB = ldsb + (buf ^ 1) * BSTR + 4096 + wid * (NB * 256);
      GLL(ga0 + kof, dA); GLL(ga1 + kof, dA + 512);
      GLL(gb0 + kof, dB);
      if constexpr (NB == 4){ GLL(gb1 + kof, dB + 512); }
    }
    const short* sA = ldsb + buf * BSTR;
    const short* sB = sA + 4096;
    short8 af[4], bfv[NB];
#pragma unroll
    for (int mi = 0; mi < 4; mi++)
      af[mi] = *(const short8*)(sA + (wm + mi * 16 + r16) * 32 + ((kb ^ rsw) << 3));
#pragma unroll
    for (int ni = 0; ni < NB; ni++)
      bfv[ni] = *(const short8*)(sB + (wn + ni * 16 + r16) * 32 + ((kb ^ rsw) << 3));
#pragma unroll
    for (int mi = 0; mi < 4; mi++)
#pragma unroll
      for (int ni = 0; ni < NB; ni++)
        acc[mi][ni] = __builtin_amdgcn_mfma_f32_16x16x32_bf16(af[mi], bfv[ni], acc[mi][ni], 0, 0, 0);
    __syncthreads();
    buf ^= 1;
  }

  if constexpr (EPI == 1){
    const int slot = bx * 2 + (wid & 1);
#pragma unroll
    for (int mi = 0; mi < 4; mi++){
#pragma unroll
      for (int q = 0; q < 4; q++){
        const int i = m0 + wm + mi * 16 + kb * 4 + q;
        float vv[NB]; float sv = 0.f, sq = 0.f;
#pragma unroll
        for (int ni = 0; ni < NB; ni++){
          const int n = n0 + wn + ni * 16 + r16;
          const float v = acc[mi][ni][q] + bias[(size_t)z * bstride + n];
          vv[ni] = v; sv += v; sq += v * v;
        }
#pragma unroll
        for (int off = 1; off < 16; off <<= 1){
          sv += __shfl_xor(sv, off, 64);
          sq += __shfl_xor(sq, off, 64);
        }
        if (i < Mg){
#pragma unroll
          for (int ni = 0; ni < NB; ni++){
            const int n = n0 + wn + ni * 16 + r16;
            outb[((size_t)e * CB + (g0 + i)) * (size_t)N + n] = f2bs(vv[ni]);
          }
          if (r16 == 0){
            float* sp = pstat + ((size_t)slot * (CE * CB) + (size_t)e * CB + (g0 + i)) * 2;
            sp[0] = sv; sp[1] = sq;
          }
        }
      }
    }
    return;
  }

  if constexpr (EPI == 6){
    const int hbase = n0 + wn;
    float wv[NB][8]; float rbv[NB];
#pragma unroll
    for (int ni = 0; ni < NB; ni++){
      const int h = hbase + ni * 16 + r16;
      rbv[ni] = bias[(size_t)z * CH + h];
      const float* wp = xtra + ((size_t)z * CH + h) * 8;
#pragma unroll
      for (int e2 = 0; e2 < 8; e2++) wv[ni][e2] = wp[e2];
    }
    const int slot = bx * 2 + (wid & 1);
#pragma unroll
    for (int mi = 0; mi < 4; mi++){
#pragma unroll
      for (int q = 0; q < 4; q++){
        float tmp[8];
#pragma unroll
        for (int e2 = 0; e2 < 8; e2++) tmp[e2] = 0.f;
#pragma unroll
        for (int ni = 0; ni < NB; ni++){
          const float v = fmaxf(acc[mi][ni][q] + rbv[ni], 0.f);
#pragma unroll
          for (int e2 = 0; e2 < 8; e2++) tmp[e2] += v * wv[ni][e2];
        }
#pragma unroll
        for (int e2 = 0; e2 < 8; e2++){
          tmp[e2] += __shfl_xor(tmp[e2], 1, 64);
          tmp[e2] += __shfl_xor(tmp[e2], 2, 64);
          tmp[e2] += __shfl_xor(tmp[e2], 4, 64);
          tmp[e2] += __shfl_xor(tmp[e2], 8, 64);
        }
        const int row = wm + mi * 16 + kb * 4 + q;
        if (r16 == 0 && m0 + row < Mg){
          float* dp = outf + ((size_t)slot * CB + (g0 + m0 + row)) * 8;
#pragma unroll
          for (int e2 = 0; e2 < 8; e2++) dp[e2] = tmp[e2];
        }
      }
    }
    return;
  }

#pragma unroll
  for (int mi = 0; mi < 4; mi++){
#pragma unroll
    for (int q = 0; q < 4; q++){
      const int i = m0 + wm + mi * 16 + kb * 4 + q;
      if (i >= Mg) continue;
#pragma unroll
      for (int ni = 0; ni < NB; ni++){
        const int n = n0 + wn + ni * 16 + r16;
        float v = acc[mi][ni][q] + bias[n];
        if constexpr (EPI == 3){
          outb[(size_t)i * (size_t)N + n] = f2bs(v);
        } else {
          outf[(size_t)i * (size_t)N + n] = v;
        }
      }
    }
  }
}

// ---------- merged launch: router(320) + GEMM1(2560, XCD-swz) + ew2t copy(8192) + ipw/opw cvt(512) ----------
__global__ __launch_bounds__(256) void k_rg1(
    const short* __restrict__ xp, const short* __restrict__ wt1, const int* __restrict__ meta,
    const float* __restrict__ eb1, short* __restrict__ hact, float* __restrict__ pstat,
    const short* __restrict__ xd, const short* __restrict__ wtR,
    const float* __restrict__ rbias, const float* __restrict__ rw2, float* __restrict__ part,
    const float* __restrict__ ew2, short* __restrict__ wt2,
    const float* __restrict__ ipw, short* __restrict__ ipwb,
    const float* __restrict__ opw, short* __restrict__ opwb){
  __shared__ __align__(16) short lds[2][8192];
  const int s = blockIdx.x;
  if (s < 320){
    const int bx = s & 15, by = (s >> 4) % MBY, bz = s / (16 * MBY);
    gemm_body<6, 4>(&lds[0][0], bx, by, bz, xd, 1536, wtR, 1536, meta, 0, 1536, CH,
                    rbias, 0, nullptr, part, nullptr, rw2, nullptr);
  } else if (s < 2880){
    const int t = s - 320;
    const int l = (t & 7) * 320 + (t >> 3);        // bijective XCD chunk swizzle
    const int bx = l % 16; const int u = l / 16; const int by = u % MBY; const int bz = u / MBY;
    gemm_body<1, 4>(&lds[0][0], bx, by, bz, xp, CD, wt1, CD, meta, 0, CD, CH, eb1, CH,
                    hact, nullptr, nullptr, nullptr, pstat);
  } else if (s < 11072){
    float (*tile)[65] = (float(*)[65])&lds[0][0];
    const int i = s - 2880;
    cvtt_tile(tile, ew2, wt2, CH, CO, i & 7, (i >> 3) & 31, i >> 8);
  } else {
    int i = ((s - 11072) * 256 + threadIdx.x) * 8;
    const int na = 1536 * 512, nb = 512 * 512;
    const float* src; short* dst;
    if (i < na){ src = ipw + i; dst = ipwb + i; }
    else { int j = i - na; if (j >= nb) return; src = opw + j; dst = opwb + j; }
    float4 u = *(const float4*)(src);
    float4 v = *(const float4*)(src + 4);
    short8 o;
    o[0]=f2bs(u.x); o[1]=f2bs(u.y); o[2]=f2bs(u.z); o[3]=f2bs(u.w);
    o[4]=f2bs(v.x); o[5]=f2bs(v.y); o[6]=f2bs(v.z); o[7]=f2bs(v.w);
    *(short8*)(dst) = o;
  }
}

// ---------- merged launch: logits (512) + GEMM2 with fused LN (1280, XCD-swizzled) ----------
__global__ __launch_bounds__(256) void k_g2l(
    const short* __restrict__ hact, const short* __restrict__ Wt,
    const int* __restrict__ goff, const float* __restrict__ pstat,
    const float* __restrict__ lng, const float* __restrict__ lnb,
    short* __restrict__ P, long pstr, const int* __restrict__ operm,
    const float* __restrict__ part, const float* __restrict__ rb2,
    int* __restrict__ tki, float* __restrict__ tkw, int* __restrict__ qrows){
  constexpr int BK = 32, KS = 1024;
  __shared__ __align__(16) short lds[2][8192];
  __shared__ float smean[128], srstd[128];

  const int s0 = blockIdx.x;
  if (s0 < 512){
    logits_body(s0, part, rb2, goff, operm, tki, tkw, qrows);
    return;
  }
  const int s = s0 - 512;
  const int l = (s & 7) * 160 + (s >> 3);
  const int bx = l % 4; const int u = l / 4; const int by = u % MBY; const int bz = u / MBY;
  const int ks = bz & 1, z = bz >> 1;
  const int r = z >> 3, e = z & 7;
  const int g0 = goff[r], Mg = goff[r + 1] - g0;
  const int m0 = by * 128;
  if (m0 >= Mg) return;
  const int n0 = bx * 128;
  const long kbase = (long)ks * KS;

  const int tid = threadIdx.x, lane = tid & 63, wid = tid >> 6;

  if (tid < 128){
    int lr = m0 + tid; if (lr > Mg - 1) lr = Mg - 1;
    const size_t rid = (size_t)e * CB + g0 + lr;
    float S = 0.f, Q = 0.f;
#pragma unroll
    for (int p = 0; p < 32; p++){
      const float2 pp = *(const float2*)(pstat + ((size_t)p * (CE * CB) + rid) * 2);
      S += pp.x; Q += pp.y;
    }
    const float mean = S * (1.f / CH);
    const float var = Q * (1.f / CH) - mean * mean;
    smean[tid] = mean;
    srstd[tid] = rsqrtf(fmaxf(var, 0.f) + 1e-5f);
  }

  const int srow = lane >> 2;
  const int c = lane & 3;
  const int dsw = (srow >> 1) & 3;

  const int lr0 = wid * 32 + srow, lr1 = lr0 + 16;
  const int cr0 = (m0 + lr0 > Mg - 1) ? (Mg - 1 - m0) : lr0;
  const int cr1 = (m0 + lr1 > Mg - 1) ? (Mg - 1 - m0) : lr1;

  const short* ga0 = hact + ((size_t)e * CB + g0 + (m0 + cr0)) * (size_t)CH + kbase + c * 8;
  const short* ga1 = hact + ((size_t)e * CB + g0 + (m0 + cr1)) * (size_t)CH + kbase + c * 8;
  const float* gp = lng + (size_t)(r * CE + e) * CH + kbase + c * 8;
  const float* bp = lnb + (size_t)(r * CE + e) * CH + kbase + c * 8;

  const short* Wb = Wt + (size_t)z * (size_t)CO * (size_t)CH;
  const int brow = n0 + wid * 32 + srow;
  const int scB = ((c ^ dsw) << 3);
  const short* gb0 = Wb + (size_t)brow * CH + kbase + scB;
  const short* gb1 = gb0 + (size_t)16 * CH;

  const int wof0 = lr0 * 32 + ((c ^ dsw) << 3);
  const int wof1 = lr1 * 32 + ((c ^ dsw) << 3);

  __syncthreads();
  const float mean0 = smean[cr0], rstd0 = srstd[cr0];
  const float mean1 = smean[cr1], rstd1 = srstd[cr1];

  const int wm = (wid >> 1) * 64, wn = (wid & 1) * 64;
  const int r16 = lane & 15, kb = lane >> 4;
  const int rsw = (r16 >> 1) & 3;

  f32x4 acc[4][4];
#pragma unroll
  for (int a = 0; a < 4; a++)
#pragma unroll
    for (int b = 0; b < 4; b++) acc[a][b] = (f32x4){0.f, 0.f, 0.f, 0.f};

  const int NT = KS / BK;
  int buf = 0;

  {
    short8 a0 = *(const short8*)(ga0);
    short8 a1 = *(const short8*)(ga1);
    float4 g01 = *(const float4*)(gp), g23 = *(const float4*)(gp + 4);
    float4 b01 = *(const float4*)(bp), b23 = *(const float4*)(bp + 4);
    short* dB = &lds[0][4096] + wid * 1024;
    GLL(gb0, dB); GLL(gb1, dB + 512);
    *(short8*)(&lds[0][0] + wof0) = ln8(a0, mean0, rstd0, g01, g23, b01, b23);
    *(short8*)(&lds[0][0] + wof1) = ln8(a1, mean1, rstd1, g01, g23, b01, b23);
  }
  __syncthreads();

  for (int t = 0; t < NT; ++t){
    short8 na0, na1; float4 ng01, ng23, nb01, nb23;
    if (t + 1 < NT){
      const int kof = (t + 1) * BK;
      na0 = *(const short8*)(ga0 + kof);
      na1 = *(const short8*)(ga1 + kof);
      ng01 = *(const float4*)(gp + kof); ng23 = *(const float4*)(gp + kof + 4);
      nb01 = *(const float4*)(bp + kof); nb23 = *(const float4*)(bp + kof + 4);
      short* dB = &lds[buf ^ 1][4096] + wid * 1024;
      GLL(gb0 + kof, dB); GLL(gb1 + kof, dB + 512);
    }
    const short* sA = &lds[buf][0];
    const short* sB = &lds[buf][4096];
    short8 af[4], bfv[4];
#pragma unroll
    for (int mi = 0; mi < 4; mi++)
      af[mi] = *(const short8*)(sA + (wm + mi * 16 + r16) * 32 + ((kb ^ rsw) << 3));
#pragma unroll
    for (int ni = 0; ni < 4; ni++)
      bfv[ni] = *(const short8*)(sB + (wn + ni * 16 + r16) * 32 + ((kb ^ rsw) << 3));
#pragma unroll
    for (int mi = 0; mi < 4; mi++)
#pragma unroll
      for (int ni = 0; ni < 4; ni++)
        acc[mi][ni] = __builtin_amdgcn_mfma_f32_16x16x32_bf16(af[mi], bfv[ni], acc[mi][ni], 0, 0, 0);
    if (t + 1 < NT){
      *(short8*)(&lds[buf ^ 1][0] + wof0) = ln8(na0, mean0, rstd0, ng01, ng23, nb01, nb23);
      *(short8*)(&lds[buf ^ 1][0] + wof1) = ln8(na1, mean1, rstd1, ng01, ng23, nb01, nb23);
    }
    __syncthreads();
    buf ^= 1;
  }

#pragma unroll
  for (int mi = 0; mi < 4; mi++){
#pragma unroll
    for (int q = 0; q < 4; q++){
      const int i = m0 + wm + mi * 16 + kb * 4 + q;
      if (i >= Mg) continue;
      const int borig = operm[g0 + i];
#pragma unroll
      for (int ni = 0; ni < 4; ni++){
        const int n = n0 + wn + ni * 16 + r16;
        P[(size_t)ks * pstr + ((size_t)borig * CE + e) * (size_t)CO + n] = f2bs(acc[mi][ni][q]);
      }
    }
  }
}

// ---------- merged launch: KV (2048, NB=2, XCD-swizzled) + Q-gather (256, NB=2) ----------
__global__ __launch_bounds__(256) void k_kvq(
    const short* __restrict__ eo, const short* __restrict__ ipwb, const float* __restrict__ ipb,
    short* __restrict__ qkv, short* __restrict__ qb, const int* __restrict__ qrows){
  __shared__ __align__(16) short lds[2][6144];   // 24 KiB -> 6 blocks/CU
  const int s = blockIdx.x;
  if (s < 2048){
    const int l = (s & 7) * 256 + (s >> 3);      // bijective XCD chunk swizzle
    const int bx = l % 16, by = l / 16;          // 16 n-blocks x 128 m-blocks
    gemm_body<3, 2>(&lds[0][0], bx, by, 0, eo, CO, ipwb + (size_t)512 * 512, CO, nullptr,
                    CB * CE, CO, 1024, ipb + 512, 0, qkv, nullptr, nullptr, nullptr, nullptr);
  } else {
    const int i = s - 2048;                      // 256: 8 n-blocks x 32 m-blocks
    gemm_body<3, 2>(&lds[0][0], i & 7, i >> 3, 0, eo, CO, ipwb, CO, nullptr,
                    CB * 2, CO, CO, ipb, 0, qb, nullptr, qrows, nullptr, nullptr);
  }
}

// ---------- proj (f32 out, NB=2) ----------
__global__ __launch_bounds__(256) void k_proj(
    const short* __restrict__ av, const short* __restrict__ opwb, const float* __restrict__ opb,
    float* __restrict__ proj){
  __shared__ __align__(16) short lds[2][6144];
  const int s = blockIdx.x;                      // 256: 8 n-blocks x 32 m-blocks
  gemm_body<4, 2>(&lds[0][0], s & 7, s >> 3, 0, av, CO, opwb, CO, nullptr,
                  CB * 2, CO, CO, opb, 0, nullptr, proj, nullptr, nullptr, nullptr);
}

// ---------- combine GEMM2 K-split partials (x2) + bias + f32 residual -> eo bf16 ----------
__global__ __launch_bounds__(256) void k_eo(const short* __restrict__ P, long pstr,
    const float* __restrict__ eb2, const float* __restrict__ x, const int* __restrict__ regime,
    short* __restrict__ eo){
  const int b = blockIdx.x, e = blockIdx.y;
  const int r = regime[b];
  const int c = threadIdx.x * 2;
  const size_t idx = (((size_t)b * CE + e) << 9) + c;
  short2 a0 = *(const short2*)(P + idx);
  short2 a1 = *(const short2*)(P + pstr + idx);
  float2 xr = *(const float2*)(x + (size_t)b * CD + c);
  float2 eb = *(const float2*)(eb2 + (((size_t)r * CE + e) << 9) + c);
  short2 o;
  o.x = f2bs(bs2f(a0.x) + bs2f(a1.x) + xr.x + eb.x);
  o.y = f2bs(bs2f(a0.y) + bs2f(a1.y) + xr.y + eb.y);
  *(short2*)(eo + idx) = o;
}

// ---------- attention over expert axis (q only for the 2 selected experts) ----------
__global__ __launch_bounds__(128) void k_attn(const short* __restrict__ qb, const short* __restrict__ kv,
    const int* __restrict__ tki, short* __restrict__ av){
  const int b = blockIdx.x;
  const int j = threadIdx.x >> 6, d = threadIdx.x & 63;
  const short* q = qb + (size_t)(b * 2 + j) * CO;
  const short* base = kv + (size_t)b * CE * 1024;
#pragma unroll
  for (int h = 0; h < 8; h++){
    const float qv = bs2f(q[h * 64 + d]);
    float sc[8];
#pragma unroll
    for (int e = 0; e < 8; e++){
      float pp = qv * bs2f(base[(size_t)e * 1024 + h * 64 + d]);
#pragma unroll
      for (int off = 32; off; off >>= 1) pp += __shfl_xor(pp, off, 64);
      sc[e] = pp * 0.125f;   // 1/sqrt(DH=64)
    }
    float m = sc[0];
#pragma unroll
    for (int e = 1; e < 8; e++) m = fmaxf(m, sc[e]);
    float den = 0.f, avd = 0.f;
#pragma unroll
    for (int e = 0; e < 8; e++){
      const float pe = __expf(sc[e] - m);
      den += pe;
      avd += pe * bs2f(base[(size_t)e * 1024 + 512 + h * 64 + d]);
    }
    av[((size_t)b * 2 + j) * CO + h * 64 + d] = f2bs(avd / den);
  }
}

// ---------- final LN + top-k combine ----------
__global__ __launch_bounds__(256) void k_final(const short* __restrict__ eo,
    const float* __restrict__ proj, const int* __restrict__ tki, const float* __restrict__ tkw,
    const float* __restrict__ ang, const float* __restrict__ anb, float* __restrict__ out){
  const int b = blockIdx.x, t = threadIdx.x;
  float o0 = 0.f, o1 = 0.f;
#pragma unroll
  for (int j = 0; j < 2; j++){
    const int s = tki[b * 2 + j];
    const float w = tkw[b * 2 + j];
    const short* ep = eo + ((size_t)b * CE + s) * CO;
    const float* pp = proj + ((size_t)b * 2 + j) * CO;
    const float v0 = bs2f(ep[t]) + pp[t];
    const float v1 = bs2f(ep[t + 256]) + pp[t + 256];
    float sm = v0 + v1, sq = v0 * v0 + v1 * v1;
    block_reduce2(sm, sq);
    const float mean = sm * (1.f / CO);
    const float rstd = rsqrtf(fmaxf(sq * (1.f / CO) - mean * mean, 0.f) + 1e-5f);
    o0 += w * ((v0 - mean) * rstd * ang[t] + anb[t]);
    o1 += w * ((v1 - mean) * rstd * ang[t + 256] + anb[t + 256]);
  }
  out[(size_t)b * CO + t] = o0;
  out[(size_t)b * CO + t + 256] = o1;
}

// ---------- launch ----------
extern "C" void kernel_launch(void* const* d_in, const int* in_sizes, int n_in,
                              void* d_out, int out_size, void* d_ws, size_t ws_size,
                              hipStream_t stream){
  const float* x    = (const float*)d_in[0];
  const int*   regime = (const int*)d_in[1];
  const float* ew1  = (const float*)d_in[3];
  const float* eb1  = (const float*)d_in[4];
  const float* lng  = (const float*)d_in[5];
  const float* lnb  = (const float*)d_in[6];
  const float* ew2  = (const float*)d_in[7];
  const float* eb2  = (const float*)d_in[8];
  const float* rw1  = (const float*)d_in[9];
  const float* rb1  = (const float*)d_in[10];
  const float* rw2  = (const float*)d_in[11];
  const float* rb2  = (const float*)d_in[12];
  const float* ipw  = (const float*)d_in[13];
  const float* ipb  = (const float*)d_in[14];
  const float* opw  = (const float*)d_in[15];
  const float* opb  = (const float*)d_in[16];
  const float* ang  = (const float*)d_in[17];
  const float* anb  = (const float*)d_in[18];
  float* out = (float*)d_out;

  char* ws = (char*)d_ws;
  int*   meta  = (int*)(ws);
  int*   perm  = (int*)(ws + (16u << 10));
  int*   tki   = (int*)(ws + (32u << 10));
  float* tkw   = (float*)(ws + (48u << 10));
  int*   qrows = (int*)(ws + (64u << 10));
  float* rbias = (float*)(ws + (80u << 10));
  short* ipwb  = (short*)(ws + (256u << 10));       // 1.5 MiB
  short* opwb  = (short*)(ws + (1792u << 10));      // 0.5 MiB
  short* xp    = (short*)(ws + (2304u << 10));      // 2 MiB
  short* eo    = (short*)(ws + (4352u << 10));      // 16 MiB
  short* hact  = (short*)(ws + (22ull << 20));      // 64 MiB, spans [22,86)
  short* qkv   = (short*)(ws + (22ull << 20));      // 32 MiB (after hact dead)
  short* qb    = (short*)(ws + (54ull << 20));      // 4 MiB (after hact dead)
  short* av    = (short*)(ws + (58ull << 20));      // 4 MiB (after hact dead)
  float* proj  = (float*)(ws + (62ull << 20));      // 8 MiB (after hact dead)
  short* wtR   = (short*)(ws + (88ull << 20));      // 24 MiB router B'
  short* wt1   = (short*)(ws + (112ull << 20));     // 64 MiB ew1t
  short* wt2   = (short*)(ws + (176ull << 20));     // 64 MiB ew2t
  short* P     = (short*)(ws + (240ull << 20));     // 32 MiB GEMM2 partials x2
  short* xd    = (short*)(ws + (272ull << 20));     // 6 MiB router A'
  float* pstat = (float*)(ws + (280ull << 20));     // 4 MiB LN stats [32][CE*CB][2]
  float* part  = (float*)(ws + (286ull << 20));     // 2 MiB logit partials [32][CB][8]
  const long PSTR = (long)CB * CE * CO;

  // 1. bucket
  k_bucket<<<1, 1024, 0, stream>>>(regime, meta, perm);
  // 2. critical-path prep: xsplit | router B'+rbias | ew1t
  k_prep<<<11264, 256, 0, stream>>>(x, perm, xp, xd, rw1, rb1, wtR, rbias, ew1, wt1);
  // 3. merged router(first) + GEMM1 + ew2t copy + ipw/opw cvt
  k_rg1<<<320 + 2560 + 8192 + 512, 256, 0, stream>>>(
      xp, wt1, meta, eb1, hact, pstat, xd, wtR, rbias, rw2, part,
      ew2, wt2, ipw, ipwb, opw, opwb);
  // 4. merged logits + GEMM2-with-fused-LN (K-split x2)
  k_g2l<<<512 + 1280, 256, 0, stream>>>(hact, wt2, meta, pstat, lng, lnb, P, PSTR, perm,
                                        part, rb2, tki, tkw, qrows);
  // 5. combine partials + residual -> eo
  k_eo<<<dim3(CB, CE), 256, 0, stream>>>(P, PSTR, eb2, x, regime, eo);
  // 6. merged KV + Q (NB=2 tiles: 24 KiB LDS, 6 blocks/CU, 2304 blocks)
  k_kvq<<<2048 + 256, 256, 0, stream>>>(eo, ipwb, ipb, qkv, qb, qrows);
  // 7. attention over expert axis
  k_attn<<<CB, 128, 0, stream>>>(qb, qkv, tki, av);
  // 8. proj (NB=2)
  k_proj<<<256, 256, 0, stream>>>(av, opwb, opb, proj);
  // 9. final LN + combine
  k_final<<<CB, 256, 0, stream>>>(eo, proj, tki, tkw, ang, anb, out);
  (void)in_sizes; (void)n_in; (void)out_size; (void)ws_size;
}

// Round 16
// 365.205 us; speedup vs baseline: 1.0220x; 1.0220x over previous
//
#include <hip/hip_runtime.h>
#include <hip/hip_bf16.h>
#include <cstddef>

typedef __attribute__((ext_vector_type(8))) short short8;
typedef __attribute__((ext_vector_type(4))) float f32x4;

constexpr int CB = 2048;   // batch
constexpr int CD = 512;    // input dim
constexpr int CH = 2048;   // expert hidden
constexpr int CO = 512;    // output dim
constexpr int CE = 8;      // experts
constexpr int CR = 4;      // regimes
constexpr int MBY = 5;     // M-tile slots per regime (Mg <= 640 guarded by m0>=Mg exit)

// ---------- helpers ----------
__device__ __forceinline__ float bs2f(short s){
  union { float f; unsigned u; } u; u.u = ((unsigned)(unsigned short)s) << 16; return u.f;
}
__device__ __forceinline__ short f2bs(float x){
  union { __hip_bfloat16 h; short s; } u; u.h = __float2bfloat16(x); return u.s;
}

#define GLL(g, l) __builtin_amdgcn_global_load_lds((const __attribute__((address_space(1))) void*)(g), (__attribute__((address_space(3))) void*)(l), 16, 0, 0)

__device__ __forceinline__ short8 ln8(short8 raw, float mean, float rstd,
                                      float4 g01, float4 g23, float4 b01, float4 b23){
  const float g[8] = {g01.x,g01.y,g01.z,g01.w,g23.x,g23.y,g23.z,g23.w};
  const float b[8] = {b01.x,b01.y,b01.z,b01.w,b23.x,b23.y,b23.z,b23.w};
  short8 o;
#pragma unroll
  for (int j = 0; j < 8; j++){
    const float v = (bs2f(raw[j]) - mean) * rstd * g[j] + b[j];
    o[j] = f2bs(fmaxf(v, 0.f));
  }
  return o;
}

__device__ __forceinline__ void block_reduce2(float& a, float& b){
#pragma unroll
  for (int off = 32; off; off >>= 1){ a += __shfl_xor(a, off, 64); b += __shfl_xor(b, off, 64); }
  __shared__ float sa[4], sb[4];
  const int wid = threadIdx.x >> 6, lane = threadIdx.x & 63;
  __syncthreads();
  if (lane == 0){ sa[wid] = a; sb[wid] = b; }
  __syncthreads();
  a = sa[0] + sa[1] + sa[2] + sa[3];
  b = sb[0] + sb[1] + sb[2] + sb[3];
}

// ---------- regime bucketing: count + scan + scatter in ONE single-block launch ----------
__global__ __launch_bounds__(1024) void k_bucket(const int* __restrict__ regime,
                                                 int* __restrict__ meta, int* __restrict__ perm){
  __shared__ int cnt[4], cur[4];
  const int t = threadIdx.x;
  if (t < 4) cnt[t] = 0;
  __syncthreads();
  const int r0 = regime[t];
  const int r1 = regime[t + 1024];
  atomicAdd(&cnt[r0], 1);
  atomicAdd(&cnt[r1], 1);
  __syncthreads();
  if (t == 0){
    const int c0 = cnt[0], c1 = cnt[1], c2 = cnt[2], c3 = cnt[3];
    meta[0] = 0; meta[1] = c0; meta[2] = c0 + c1; meta[3] = c0 + c1 + c2; meta[4] = c0 + c1 + c2 + c3;
    cur[0] = 0; cur[1] = c0; cur[2] = c0 + c1; cur[3] = c0 + c1 + c2;
  }
  __syncthreads();
  { int p = atomicAdd(&cur[r0], 1); perm[p] = t; }
  { int p = atomicAdd(&cur[r1], 1); perm[p] = t + 1024; }
}

// ---------- 64x64 f32 [K][N] -> bf16 [N][K] transpose+convert tile ----------
__device__ __forceinline__ void cvtt_tile(float (*tile)[65], const float* __restrict__ in,
                                          short* __restrict__ outp, int K, int N,
                                          int bx, int by, int bz){
  const int k0 = by * 64, n0 = bx * 64;
  const float* src = in + (size_t)bz * K * N;
  short* dst = outp + (size_t)bz * K * N;
  const int t = threadIdx.x;
  const int kk = t >> 4, nq = (t & 15) * 4;
#pragma unroll
  for (int j = 0; j < 4; j++){
    float4 v = *(const float4*)(src + (size_t)(k0 + kk + j * 16) * N + n0 + nq);
    tile[kk + j * 16][nq] = v.x; tile[kk + j * 16][nq + 1] = v.y;
    tile[kk + j * 16][nq + 2] = v.z; tile[kk + j * 16][nq + 3] = v.w;
  }
  __syncthreads();
  const int n = t >> 2, kq = (t & 3) * 16;
  short8 o0, o1;
#pragma unroll
  for (int j = 0; j < 8; j++) o0[j] = f2bs(tile[kq + j][n]);
#pragma unroll
  for (int j = 0; j < 8; j++) o1[j] = f2bs(tile[kq + 8 + j][n]);
  short* drow = dst + (size_t)(n0 + n) * K + k0 + kq;
  *(short8*)(drow) = o0;
  *(short8*)(drow + 8) = o1;
}

// ---------- prep (critical-path only): xsplit | rwt | cvt_t(ew1) ----------
__global__ __launch_bounds__(256) void k_prep(
    const float* __restrict__ x, const int* __restrict__ perm,
    short* __restrict__ xp, short* __restrict__ xd,
    const float* __restrict__ rw1, const float* __restrict__ rb1,
    short* __restrict__ wtR, float* __restrict__ rbias,
    const float* __restrict__ ew1, short* __restrict__ wt1){
  __shared__ float tile[64][65];
  const int s = blockIdx.x;
  const int t = threadIdx.x;
  if (s < 2048){
    const int i = s, b = perm[i], c = t * 2;
    float2 v = *(const float2*)(x + (size_t)b * CD + c);
    short2 hi; hi.x = f2bs(v.x); hi.y = f2bs(v.y);
    short2 lo; lo.x = f2bs(v.x - bs2f(hi.x)); lo.y = f2bs(v.y - bs2f(hi.y));
    *(short2*)(xp + (size_t)i * CD + c) = hi;
    short* row = xd + (size_t)i * 1536;
    *(short2*)(row + c) = hi;
    *(short2*)(row + 512 + c) = hi;
    *(short2*)(row + 1024 + c) = lo;
    return;
  }
  if (s < 3072){
    // rwt: router B' [r][n][1536] = [Whi | Wlo | Whi]; rbias at by==0
    const int i = s - 2048;
    const int bx = i & 31, by = (i >> 5) & 7, r = i >> 8;
    const int k0 = by * 64, n0 = bx * 64;
    const float* src = rw1 + (size_t)r * (CD + CR) * CH;
    short* dst = wtR + (size_t)r * CH * 1536;
    if (by == 0 && t < 64){
      const int n = n0 + t;
      rbias[r * CH + n] = rb1[(size_t)r * CH + n] + src[((size_t)(CD + r)) * CH + n];
    }
    const int kk = t >> 4, nq = (t & 15) * 4;
#pragma unroll
    for (int j = 0; j < 4; j++){
      float4 v = *(const float4*)(src + (size_t)(k0 + kk + j * 16) * CH + n0 + nq);
      tile[kk + j * 16][nq] = v.x; tile[kk + j * 16][nq + 1] = v.y;
      tile[kk + j * 16][nq + 2] = v.z; tile[kk + j * 16][nq + 3] = v.w;
    }
    __syncthreads();
    const int n = t >> 2, kq = (t & 3) * 16;
    short8 h0, h1, l0, l1;
#pragma unroll
    for (int j = 0; j < 8; j++){
      float f = tile[kq + j][n];
      short h = f2bs(f); h0[j] = h; l0[j] = f2bs(f - bs2f(h));
    }
#pragma unroll
    for (int j = 0; j < 8; j++){
      float f = tile[kq + 8 + j][n];
      short h = f2bs(f); h1[j] = h; l1[j] = f2bs(f - bs2f(h));
    }
    short* drow = dst + (size_t)(n0 + n) * 1536;
    *(short8*)(drow + k0 + kq) = h0;        *(short8*)(drow + k0 + kq + 8) = h1;
    *(short8*)(drow + 512 + k0 + kq) = l0;  *(short8*)(drow + 512 + k0 + kq + 8) = l1;
    *(short8*)(drow + 1024 + k0 + kq) = h0; *(short8*)(drow + 1024 + k0 + kq + 8) = h1;
    return;
  }
  {
    const int i = s - 3072;                 // ew1: [32 z][8 k][32 n]
    cvtt_tile(tile, ew1, wt1, CD, CH, i & 31, (i >> 5) & 7, i >> 8);
  }
}

// ---------- logits body: reduce 32 partials + softmax + top-2 + qrows ----------
__device__ __forceinline__ void logits_body(int blk,
    const float* __restrict__ part, const float* __restrict__ rb2,
    const int* __restrict__ meta, const int* __restrict__ perm,
    int* __restrict__ tki, float* __restrict__ tkw, int* __restrict__ qrows){
  const int wid = threadIdx.x >> 6, lane = threadIdx.x & 63;
  const int i = blk * 4 + wid;
  const int r = (i >= meta[1]) + (i >= meta[2]) + (i >= meta[3]);
  const int p0 = lane >> 3, e = lane & 7;
  float v = 0.f;
#pragma unroll
  for (int j = 0; j < 4; j++)
    v += part[((size_t)(p0 + 8 * j) * CB + i) * 8 + e];
  v += __shfl_xor(v, 8, 64);
  v += __shfl_xor(v, 16, 64);
  v += __shfl_xor(v, 32, 64);
  v += rb2[r * CE + e];
  float l8[8];
#pragma unroll
  for (int e2 = 0; e2 < 8; e2++) l8[e2] = __shfl(v, e2, 64);
  if (lane == 0){
    int i1 = 0; float m1 = l8[0];
#pragma unroll
    for (int e2 = 1; e2 < 8; e2++) if (l8[e2] > m1){ m1 = l8[e2]; i1 = e2; }
    int i2 = -1; float m2 = -1e30f;
#pragma unroll
    for (int e2 = 0; e2 < 8; e2++) if (e2 != i1 && l8[e2] > m2){ m2 = l8[e2]; i2 = e2; }
    const float e2w = __expf(m2 - m1);
    const float w1 = 1.f / (1.f + e2w);
    const int b = perm[i];
    tki[b * 2] = i1; tki[b * 2 + 1] = i2;
    tkw[b * 2] = w1; tkw[b * 2 + 1] = e2w * w1;
    qrows[b * 2] = b * CE + i1; qrows[b * 2 + 1] = b * CE + i2;
  }
}

// ---------- bf16 MFMA GEMM body, 128x(NB*32) tile, BK=32, global_load_lds, 2-phase dbuf ----------
// NB=4 everywhere this round (R15's NB=2 tail tiling regressed: doubled A re-reads).
// EPI: 1 = expert GEMM1 (+bias raw pre-LN out, LN stat partials)
//      3 = plain bf16 out (+bias); optional A row-gather via operm
//      4 = plain f32 out (+bias)
//      6 = fused router (+rbias, relu, contract with rw2 -> logit partials)
template<int EPI, int NB>
__device__ __forceinline__ void gemm_body(
    short* __restrict__ ldsb,
    int bx, int by, int bz,
    const short* __restrict__ A, long lda,
    const short* __restrict__ Wt, long ldw,
    const int* __restrict__ goff, int fixedM, int Ksub, int N,
    const float* __restrict__ bias, long bstride,
    short* __restrict__ outb, float* __restrict__ outf,
    const int* __restrict__ operm, const float* __restrict__ xtra,
    float* __restrict__ pstat){
  constexpr int BK = 32;
  constexpr int BSTR = 4096 + NB * 1024;

  const int z = bz;
  int g0 = 0, Mg = fixedM;
  if (goff){ const int r = (EPI == 6) ? z : (z >> 3); g0 = goff[r]; Mg = goff[r + 1] - g0; }
  const int m0 = by * 128;
  if (m0 >= Mg) return;
  const int n0 = bx * (NB * 32);
  const int e = z & 7;

  const short* Ab;
  if constexpr (EPI == 1 || EPI == 6) Ab = A + (size_t)g0 * (size_t)lda;
  else Ab = A;
  const short* Wb = Wt + (size_t)z * (size_t)N * (size_t)ldw;

  const int tid = threadIdx.x;
  const int lane = tid & 63, wid = tid >> 6;
  const int srow = lane >> 2;
  const int sc = (((lane & 3) ^ ((srow >> 1) & 3)) << 3);  // swizzled source k-chunk (shorts)

  int ar0 = m0 + wid * 32 + srow;
  int ar1 = ar0 + 16;
  if (ar0 > Mg - 1) ar0 = Mg - 1;
  if (ar1 > Mg - 1) ar1 = Mg - 1;
  if constexpr (EPI == 3){
    if (operm){ ar0 = operm[ar0]; ar1 = operm[ar1]; }
  }
  const short* ga0 = Ab + (size_t)ar0 * lda + sc;
  const short* ga1 = Ab + (size_t)ar1 * lda + sc;
  const int brow = n0 + wid * (NB * 8) + srow;
  const short* gb0 = Wb + (size_t)brow * ldw + sc;
  const short* gb1 = gb0 + (size_t)16 * ldw;

  const int wm = (wid >> 1) * 64, wn = (wid & 1) * (NB * 16);
  const int r16 = lane & 15, kb = lane >> 4;
  const int rsw = (r16 >> 1) & 3;

  f32x4 acc[4][NB];
#pragma unroll
  for (int a = 0; a < 4; a++)
#pragma unroll
    for (int b = 0; b < NB; b++) acc[a][b] = (f32x4){0.f, 0.f, 0.f, 0.f};

  const int NT = Ksub / BK;
  int buf = 0;

  {
    short* dA = ldsb + wid * 1024;
    short* dB = ldsb + 4096 + wid * (NB * 256);
    GLL(ga0, dA); GLL(ga1, dA + 512);
    GLL(gb0, dB);
    if constexpr (NB == 4){ GLL(gb1, dB + 512); }
  }
  __syncthreads();

  for (int t = 0; t < NT; ++t){
    if (t + 1 < NT){
      const int kof = (t + 1) * BK;
      short* dA = ldsb + (buf ^ 1) * BSTR + wid * 1024;
      short* dB = ldsb + (buf ^ 1) * BSTR + 4096 + wid * (NB * 256);
      GLL(ga0 + kof, dA); GLL(ga1 + kof, dA + 512);
      GLL(gb0 + kof, dB);
      if constexpr (NB == 4){ GLL(gb1 + kof, dB + 512); }
    }
    const short* sA = ldsb + buf * BSTR;
    const short* sB = sA + 4096;
    short8 af[4], bfv[NB];
#pragma unroll
    for (int mi = 0; mi < 4; mi++)
      af[mi] = *(const short8*)(sA + (wm + mi * 16 + r16) * 32 + ((kb ^ rsw) << 3));
#pragma unroll
    for (int ni = 0; ni < NB; ni++)
      bfv[ni] = *(const short8*)(sB + (wn + ni * 16 + r16) * 32 + ((kb ^ rsw) << 3));
#pragma unroll
    for (int mi = 0; mi < 4; mi++)
#pragma unroll
      for (int ni = 0; ni < NB; ni++)
        acc[mi][ni] = __builtin_amdgcn_mfma_f32_16x16x32_bf16(af[mi], bfv[ni], acc[mi][ni], 0, 0, 0);
    __syncthreads();
    buf ^= 1;
  }

  if constexpr (EPI == 1){
    const int slot = bx * 2 + (wid & 1);
#pragma unroll
    for (int mi = 0; mi < 4; mi++){
#pragma unroll
      for (int q = 0; q < 4; q++){
        const int i = m0 + wm + mi * 16 + kb * 4 + q;
        float vv[NB]; float sv = 0.f, sq = 0.f;
#pragma unroll
        for (int ni = 0; ni < NB; ni++){
          const int n = n0 + wn + ni * 16 + r16;
          const float v = acc[mi][ni][q] + bias[(size_t)z * bstride + n];
          vv[ni] = v; sv += v; sq += v * v;
        }
#pragma unroll
        for (int off = 1; off < 16; off <<= 1){
          sv += __shfl_xor(sv, off, 64);
          sq += __shfl_xor(sq, off, 64);
        }
        if (i < Mg){
#pragma unroll
          for (int ni = 0; ni < NB; ni++){
            const int n = n0 + wn + ni * 16 + r16;
            outb[((size_t)e * CB + (g0 + i)) * (size_t)N + n] = f2bs(vv[ni]);
          }
          if (r16 == 0){
            float* sp = pstat + ((size_t)slot * (CE * CB) + (size_t)e * CB + (g0 + i)) * 2;
            sp[0] = sv; sp[1] = sq;
          }
        }
      }
    }
    return;
  }

  if constexpr (EPI == 6){
    const int hbase = n0 + wn;
    float wv[NB][8]; float rbv[NB];
#pragma unroll
    for (int ni = 0; ni < NB; ni++){
      const int h = hbase + ni * 16 + r16;
      rbv[ni] = bias[(size_t)z * CH + h];
      const float* wp = xtra + ((size_t)z * CH + h) * 8;
#pragma unroll
      for (int e2 = 0; e2 < 8; e2++) wv[ni][e2] = wp[e2];
    }
    const int slot = bx * 2 + (wid & 1);
#pragma unroll
    for (int mi = 0; mi < 4; mi++){
#pragma unroll
      for (int q = 0; q < 4; q++){
        float tmp[8];
#pragma unroll
        for (int e2 = 0; e2 < 8; e2++) tmp[e2] = 0.f;
#pragma unroll
        for (int ni = 0; ni < NB; ni++){
          const float v = fmaxf(acc[mi][ni][q] + rbv[ni], 0.f);
#pragma unroll
          for (int e2 = 0; e2 < 8; e2++) tmp[e2] += v * wv[ni][e2];
        }
#pragma unroll
        for (int e2 = 0; e2 < 8; e2++){
          tmp[e2] += __shfl_xor(tmp[e2], 1, 64);
          tmp[e2] += __shfl_xor(tmp[e2], 2, 64);
          tmp[e2] += __shfl_xor(tmp[e2], 4, 64);
          tmp[e2] += __shfl_xor(tmp[e2], 8, 64);
        }
        const int row = wm + mi * 16 + kb * 4 + q;
        if (r16 == 0 && m0 + row < Mg){
          float* dp = outf + ((size_t)slot * CB + (g0 + m0 + row)) * 8;
#pragma unroll
          for (int e2 = 0; e2 < 8; e2++) dp[e2] = tmp[e2];
        }
      }
    }
    return;
  }

#pragma unroll
  for (int mi = 0; mi < 4; mi++){
#pragma unroll
    for (int q = 0; q < 4; q++){
      const int i = m0 + wm + mi * 16 + kb * 4 + q;
      if (i >= Mg) continue;
#pragma unroll
      for (int ni = 0; ni < NB; ni++){
        const int n = n0 + wn + ni * 16 + r16;
        float v = acc[mi][ni][q] + bias[n];
        if constexpr (EPI == 3){
          outb[(size_t)i * (size_t)N + n] = f2bs(v);
        } else {
          outf[(size_t)i * (size_t)N + n] = v;
        }
      }
    }
  }
}

// ---------- merged launch: router(320) + GEMM1(2560, XCD-swz) + ew2t copy(8192) + ipw/opw cvt(512) ----------
__global__ __launch_bounds__(256) void k_rg1(
    const short* __restrict__ xp, const short* __restrict__ wt1, const int* __restrict__ meta,
    const float* __restrict__ eb1, short* __restrict__ hact, float* __restrict__ pstat,
    const short* __restrict__ xd, const short* __restrict__ wtR,
    const float* __restrict__ rbias, const float* __restrict__ rw2, float* __restrict__ part,
    const float* __restrict__ ew2, short* __restrict__ wt2,
    const float* __restrict__ ipw, short* __restrict__ ipwb,
    const float* __restrict__ opw, short* __restrict__ opwb){
  __shared__ __align__(16) short lds[2][8192];
  const int s = blockIdx.x;
  if (s < 320){
    const int bx = s & 15, by = (s >> 4) % MBY, bz = s / (16 * MBY);
    gemm_body<6, 4>(&lds[0][0], bx, by, bz, xd, 1536, wtR, 1536, meta, 0, 1536, CH,
                    rbias, 0, nullptr, part, nullptr, rw2, nullptr);
  } else if (s < 2880){
    const int t = s - 320;
    const int l = (t & 7) * 320 + (t >> 3);        // bijective XCD chunk swizzle
    const int bx = l % 16; const int u = l / 16; const int by = u % MBY; const int bz = u / MBY;
    gemm_body<1, 4>(&lds[0][0], bx, by, bz, xp, CD, wt1, CD, meta, 0, CD, CH, eb1, CH,
                    hact, nullptr, nullptr, nullptr, pstat);
  } else if (s < 11072){
    float (*tile)[65] = (float(*)[65])&lds[0][0];
    const int i = s - 2880;
    cvtt_tile(tile, ew2, wt2, CH, CO, i & 7, (i >> 3) & 31, i >> 8);
  } else {
    int i = ((s - 11072) * 256 + threadIdx.x) * 8;
    const int na = 1536 * 512, nb = 512 * 512;
    const float* src; short* dst;
    if (i < na){ src = ipw + i; dst = ipwb + i; }
    else { int j = i - na; if (j >= nb) return; src = opw + j; dst = opwb + j; }
    float4 u = *(const float4*)(src);
    float4 v = *(const float4*)(src + 4);
    short8 o;
    o[0]=f2bs(u.x); o[1]=f2bs(u.y); o[2]=f2bs(u.z); o[3]=f2bs(u.w);
    o[4]=f2bs(v.x); o[5]=f2bs(v.y); o[6]=f2bs(v.z); o[7]=f2bs(v.w);
    *(short8*)(dst) = o;
  }
}

// ---------- merged launch: logits (512) + GEMM2 with fused LN (1280, XCD-swizzled) ----------
__global__ __launch_bounds__(256) void k_g2l(
    const short* __restrict__ hact, const short* __restrict__ Wt,
    const int* __restrict__ goff, const float* __restrict__ pstat,
    const float* __restrict__ lng, const float* __restrict__ lnb,
    short* __restrict__ P, long pstr, const int* __restrict__ operm,
    const float* __restrict__ part, const float* __restrict__ rb2,
    int* __restrict__ tki, float* __restrict__ tkw, int* __restrict__ qrows){
  constexpr int BK = 32, KS = 1024;
  __shared__ __align__(16) short lds[2][8192];
  __shared__ float smean[128], srstd[128];

  const int s0 = blockIdx.x;
  if (s0 < 512){
    logits_body(s0, part, rb2, goff, operm, tki, tkw, qrows);
    return;
  }
  const int s = s0 - 512;
  const int l = (s & 7) * 160 + (s >> 3);
  const int bx = l % 4; const int u = l / 4; const int by = u % MBY; const int bz = u / MBY;
  const int ks = bz & 1, z = bz >> 1;
  const int r = z >> 3, e = z & 7;
  const int g0 = goff[r], Mg = goff[r + 1] - g0;
  const int m0 = by * 128;
  if (m0 >= Mg) return;
  const int n0 = bx * 128;
  const long kbase = (long)ks * KS;

  const int tid = threadIdx.x, lane = tid & 63, wid = tid >> 6;

  if (tid < 128){
    int lr = m0 + tid; if (lr > Mg - 1) lr = Mg - 1;
    const size_t rid = (size_t)e * CB + g0 + lr;
    float S = 0.f, Q = 0.f;
#pragma unroll
    for (int p = 0; p < 32; p++){
      const float2 pp = *(const float2*)(pstat + ((size_t)p * (CE * CB) + rid) * 2);
      S += pp.x; Q += pp.y;
    }
    const float mean = S * (1.f / CH);
    const float var = Q * (1.f / CH) - mean * mean;
    smean[tid] = mean;
    srstd[tid] = rsqrtf(fmaxf(var, 0.f) + 1e-5f);
  }

  const int srow = lane >> 2;
  const int c = lane & 3;
  const int dsw = (srow >> 1) & 3;

  const int lr0 = wid * 32 + srow, lr1 = lr0 + 16;
  const int cr0 = (m0 + lr0 > Mg - 1) ? (Mg - 1 - m0) : lr0;
  const int cr1 = (m0 + lr1 > Mg - 1) ? (Mg - 1 - m0) : lr1;

  const short* ga0 = hact + ((size_t)e * CB + g0 + (m0 + cr0)) * (size_t)CH + kbase + c * 8;
  const short* ga1 = hact + ((size_t)e * CB + g0 + (m0 + cr1)) * (size_t)CH + kbase + c * 8;
  const float* gp = lng + (size_t)(r * CE + e) * CH + kbase + c * 8;
  const float* bp = lnb + (size_t)(r * CE + e) * CH + kbase + c * 8;

  const short* Wb = Wt + (size_t)z * (size_t)CO * (size_t)CH;
  const int brow = n0 + wid * 32 + srow;
  const int scB = ((c ^ dsw) << 3);
  const short* gb0 = Wb + (size_t)brow * CH + kbase + scB;
  const short* gb1 = gb0 + (size_t)16 * CH;

  const int wof0 = lr0 * 32 + ((c ^ dsw) << 3);
  const int wof1 = lr1 * 32 + ((c ^ dsw) << 3);

  __syncthreads();
  const float mean0 = smean[cr0], rstd0 = srstd[cr0];
  const float mean1 = smean[cr1], rstd1 = srstd[cr1];

  const int wm = (wid >> 1) * 64, wn = (wid & 1) * 64;
  const int r16 = lane & 15, kb = lane >> 4;
  const int rsw = (r16 >> 1) & 3;

  f32x4 acc[4][4];
#pragma unroll
  for (int a = 0; a < 4; a++)
#pragma unroll
    for (int b = 0; b < 4; b++) acc[a][b] = (f32x4){0.f, 0.f, 0.f, 0.f};

  const int NT = KS / BK;
  int buf = 0;

  {
    short8 a0 = *(const short8*)(ga0);
    short8 a1 = *(const short8*)(ga1);
    float4 g01 = *(const float4*)(gp), g23 = *(const float4*)(gp + 4);
    float4 b01 = *(const float4*)(bp), b23 = *(const float4*)(bp + 4);
    short* dB = &lds[0][4096] + wid * 1024;
    GLL(gb0, dB); GLL(gb1, dB + 512);
    *(short8*)(&lds[0][0] + wof0) = ln8(a0, mean0, rstd0, g01, g23, b01, b23);
    *(short8*)(&lds[0][0] + wof1) = ln8(a1, mean1, rstd1, g01, g23, b01, b23);
  }
  __syncthreads();

  for (int t = 0; t < NT; ++t){
    short8 na0, na1; float4 ng01, ng23, nb01, nb23;
    if (t + 1 < NT){
      const int kof = (t + 1) * BK;
      na0 = *(const short8*)(ga0 + kof);
      na1 = *(const short8*)(ga1 + kof);
      ng01 = *(const float4*)(gp + kof); ng23 = *(const float4*)(gp + kof + 4);
      nb01 = *(const float4*)(bp + kof); nb23 = *(const float4*)(bp + kof + 4);
      short* dB = &lds[buf ^ 1][4096] + wid * 1024;
      GLL(gb0 + kof, dB); GLL(gb1 + kof, dB + 512);
    }
    const short* sA = &lds[buf][0];
    const short* sB = &lds[buf][4096];
    short8 af[4], bfv[4];
#pragma unroll
    for (int mi = 0; mi < 4; mi++)
      af[mi] = *(const short8*)(sA + (wm + mi * 16 + r16) * 32 + ((kb ^ rsw) << 3));
#pragma unroll
    for (int ni = 0; ni < 4; ni++)
      bfv[ni] = *(const short8*)(sB + (wn + ni * 16 + r16) * 32 + ((kb ^ rsw) << 3));
#pragma unroll
    for (int mi = 0; mi < 4; mi++)
#pragma unroll
      for (int ni = 0; ni < 4; ni++)
        acc[mi][ni] = __builtin_amdgcn_mfma_f32_16x16x32_bf16(af[mi], bfv[ni], acc[mi][ni], 0, 0, 0);
    if (t + 1 < NT){
      *(short8*)(&lds[buf ^ 1][0] + wof0) = ln8(na0, mean0, rstd0, ng01, ng23, nb01, nb23);
      *(short8*)(&lds[buf ^ 1][0] + wof1) = ln8(na1, mean1, rstd1, ng01, ng23, nb01, nb23);
    }
    __syncthreads();
    buf ^= 1;
  }

#pragma unroll
  for (int mi = 0; mi < 4; mi++){
#pragma unroll
    for (int q = 0; q < 4; q++){
      const int i = m0 + wm + mi * 16 + kb * 4 + q;
      if (i >= Mg) continue;
      const int borig = operm[g0 + i];
#pragma unroll
      for (int ni = 0; ni < 4; ni++){
        const int n = n0 + wn + ni * 16 + r16;
        P[(size_t)ks * pstr + ((size_t)borig * CE + e) * (size_t)CO + n] = f2bs(acc[mi][ni][q]);
      }
    }
  }
}

// ---------- merged launch: KV (1024 XCD-swizzled) + Q-gather (128) ----------
__global__ __launch_bounds__(256) void k_kvq(
    const short* __restrict__ eo, const short* __restrict__ ipwb, const float* __restrict__ ipb,
    short* __restrict__ qkv, short* __restrict__ qb, const int* __restrict__ qrows){
  __shared__ __align__(16) short lds[2][8192];
  const int s = blockIdx.x;
  if (s < 1024){
    const int chunk = 128;
    const int l = (s & 7) * chunk + (s >> 3);
    const int bx = l % 8, by = l / 8;
    gemm_body<3, 4>(&lds[0][0], bx, by, 0, eo, CO, ipwb + (size_t)512 * 512, CO, nullptr,
                    CB * CE, CO, 1024, ipb + 512, 0, qkv, nullptr, nullptr, nullptr, nullptr);
  } else {
    const int i = s - 1024;
    gemm_body<3, 4>(&lds[0][0], i & 3, i >> 2, 0, eo, CO, ipwb, CO, nullptr,
                    CB * 2, CO, CO, ipb, 0, qb, nullptr, qrows, nullptr, nullptr);
  }
}

// ---------- proj (f32 out) ----------
__global__ __launch_bounds__(256) void k_proj(
    const short* __restrict__ av, const short* __restrict__ opwb, const float* __restrict__ opb,
    float* __restrict__ proj){
  __shared__ __align__(16) short lds[2][8192];
  gemm_body<4, 4>(&lds[0][0], blockIdx.x, blockIdx.y, 0, av, CO, opwb, CO, nullptr,
                  CB * 2, CO, CO, opb, 0, nullptr, proj, nullptr, nullptr, nullptr);
}

// ---------- combine GEMM2 K-split partials (x2) + bias + f32 residual -> eo bf16 ----------
__global__ __launch_bounds__(256) void k_eo(const short* __restrict__ P, long pstr,
    const float* __restrict__ eb2, const float* __restrict__ x, const int* __restrict__ regime,
    short* __restrict__ eo){
  const int b = blockIdx.x, e = blockIdx.y;
  const int r = regime[b];
  const int c = threadIdx.x * 2;
  const size_t idx = (((size_t)b * CE + e) << 9) + c;
  short2 a0 = *(const short2*)(P + idx);
  short2 a1 = *(const short2*)(P + pstr + idx);
  float2 xr = *(const float2*)(x + (size_t)b * CD + c);
  float2 eb = *(const float2*)(eb2 + (((size_t)r * CE + e) << 9) + c);
  short2 o;
  o.x = f2bs(bs2f(a0.x) + bs2f(a1.x) + xr.x + eb.x);
  o.y = f2bs(bs2f(a0.y) + bs2f(a1.y) + xr.y + eb.y);
  *(short2*)(eo + idx) = o;
}

// ---------- attention over expert axis (q only for the 2 selected experts) ----------
__global__ __launch_bounds__(128) void k_attn(const short* __restrict__ qb, const short* __restrict__ kv,
    const int* __restrict__ tki, short* __restrict__ av){
  const int b = blockIdx.x;
  const int j = threadIdx.x >> 6, d = threadIdx.x & 63;
  const short* q = qb + (size_t)(b * 2 + j) * CO;
  const short* base = kv + (size_t)b * CE * 1024;
#pragma unroll
  for (int h = 0; h < 8; h++){
    const float qv = bs2f(q[h * 64 + d]);
    float sc[8];
#pragma unroll
    for (int e = 0; e < 8; e++){
      float pp = qv * bs2f(base[(size_t)e * 1024 + h * 64 + d]);
#pragma unroll
      for (int off = 32; off; off >>= 1) pp += __shfl_xor(pp, off, 64);
      sc[e] = pp * 0.125f;   // 1/sqrt(DH=64)
    }
    float m = sc[0];
#pragma unroll
    for (int e = 1; e < 8; e++) m = fmaxf(m, sc[e]);
    float den = 0.f, avd = 0.f;
#pragma unroll
    for (int e = 0; e < 8; e++){
      const float pe = __expf(sc[e] - m);
      den += pe;
      avd += pe * bs2f(base[(size_t)e * 1024 + 512 + h * 64 + d]);
    }
    av[((size_t)b * 2 + j) * CO + h * 64 + d] = f2bs(avd / den);
  }
}

// ---------- final LN + top-k combine ----------
__global__ __launch_bounds__(256) void k_final(const short* __restrict__ eo,
    const float* __restrict__ proj, const int* __restrict__ tki, const float* __restrict__ tkw,
    const float* __restrict__ ang, const float* __restrict__ anb, float* __restrict__ out){
  const int b = blockIdx.x, t = threadIdx.x;
  float o0 = 0.f, o1 = 0.f;
#pragma unroll
  for (int j = 0; j < 2; j++){
    const int s = tki[b * 2 + j];
    const float w = tkw[b * 2 + j];
    const short* ep = eo + ((size_t)b * CE + s) * CO;
    const float* pp = proj + ((size_t)b * 2 + j) * CO;
    const float v0 = bs2f(ep[t]) + pp[t];
    const float v1 = bs2f(ep[t + 256]) + pp[t + 256];
    float sm = v0 + v1, sq = v0 * v0 + v1 * v1;
    block_reduce2(sm, sq);
    const float mean = sm * (1.f / CO);
    const float rstd = rsqrtf(fmaxf(sq * (1.f / CO) - mean * mean, 0.f) + 1e-5f);
    o0 += w * ((v0 - mean) * rstd * ang[t] + anb[t]);
    o1 += w * ((v1 - mean) * rstd * ang[t + 256] + anb[t + 256]);
  }
  out[(size_t)b * CO + t] = o0;
  out[(size_t)b * CO + t + 256] = o1;
}

// ---------- launch ----------
extern "C" void kernel_launch(void* const* d_in, const int* in_sizes, int n_in,
                              void* d_out, int out_size, void* d_ws, size_t ws_size,
                              hipStream_t stream){
  const float* x    = (const float*)d_in[0];
  const int*   regime = (const int*)d_in[1];
  const float* ew1  = (const float*)d_in[3];
  const float* eb1  = (const float*)d_in[4];
  const float* lng  = (const float*)d_in[5];
  const float* lnb  = (const float*)d_in[6];
  const float* ew2  = (const float*)d_in[7];
  const float* eb2  = (const float*)d_in[8];
  const float* rw1  = (const float*)d_in[9];
  const float* rb1  = (const float*)d_in[10];
  const float* rw2  = (const float*)d_in[11];
  const float* rb2  = (const float*)d_in[12];
  const float* ipw  = (const float*)d_in[13];
  const float* ipb  = (const float*)d_in[14];
  const float* opw  = (const float*)d_in[15];
  const float* opb  = (const float*)d_in[16];
  const float* ang  = (const float*)d_in[17];
  const float* anb  = (const float*)d_in[18];
  float* out = (float*)d_out;

  char* ws = (char*)d_ws;
  int*   meta  = (int*)(ws);
  int*   perm  = (int*)(ws + (16u << 10));
  int*   tki   = (int*)(ws + (32u << 10));
  float* tkw   = (float*)(ws + (48u << 10));
  int*   qrows = (int*)(ws + (64u << 10));
  float* rbias = (float*)(ws + (80u << 10));
  short* ipwb  = (short*)(ws + (256u << 10));       // 1.5 MiB
  short* opwb  = (short*)(ws + (1792u << 10));      // 0.5 MiB
  short* xp    = (short*)(ws + (2304u << 10));      // 2 MiB
  short* eo    = (short*)(ws + (4352u << 10));      // 16 MiB
  short* hact  = (short*)(ws + (22ull << 20));      // 64 MiB, spans [22,86)
  short* qkv   = (short*)(ws + (22ull << 20));      // 32 MiB (after hact dead)
  short* qb    = (short*)(ws + (54ull << 20));      // 4 MiB (after hact dead)
  short* av    = (short*)(ws + (58ull << 20));      // 4 MiB (after hact dead)
  float* proj  = (float*)(ws + (62ull << 20));      // 8 MiB (after hact dead)
  short* wtR   = (short*)(ws + (88ull << 20));      // 24 MiB router B'
  short* wt1   = (short*)(ws + (112ull << 20));     // 64 MiB ew1t
  short* wt2   = (short*)(ws + (176ull << 20));     // 64 MiB ew2t
  short* P     = (short*)(ws + (240ull << 20));     // 32 MiB GEMM2 partials x2
  short* xd    = (short*)(ws + (272ull << 20));     // 6 MiB router A'
  float* pstat = (float*)(ws + (280ull << 20));     // 4 MiB LN stats [32][CE*CB][2]
  float* part  = (float*)(ws + (286ull << 20));     // 2 MiB logit partials [32][CB][8]
  const long PSTR = (long)CB * CE * CO;

  // 1. bucket
  k_bucket<<<1, 1024, 0, stream>>>(regime, meta, perm);
  // 2. critical-path prep: xsplit | router B'+rbias | ew1t
  k_prep<<<11264, 256, 0, stream>>>(x, perm, xp, xd, rw1, rb1, wtR, rbias, ew1, wt1);
  // 3. merged router(first) + GEMM1 + ew2t copy + ipw/opw cvt
  k_rg1<<<320 + 2560 + 8192 + 512, 256, 0, stream>>>(
      xp, wt1, meta, eb1, hact, pstat, xd, wtR, rbias, rw2, part,
      ew2, wt2, ipw, ipwb, opw, opwb);
  // 4. merged logits + GEMM2-with-fused-LN (K-split x2)
  k_g2l<<<512 + 1280, 256, 0, stream>>>(hact, wt2, meta, pstat, lng, lnb, P, PSTR, perm,
                                        part, rb2, tki, tkw, qrows);
  // 5. combine partials + residual -> eo
  k_eo<<<dim3(CB, CE), 256, 0, stream>>>(P, PSTR, eb2, x, regime, eo);
  // 6. merged KV + Q (NB=4, R14 config)
  k_kvq<<<1024 + 128, 256, 0, stream>>>(eo, ipwb, ipb, qkv, qb, qrows);
  // 7. attention over expert axis
  k_attn<<<CB, 128, 0, stream>>>(qb, qkv, tki, av);
  // 8. proj
  k_proj<<<dim3(4, 32), 256, 0, stream>>>(av, opwb, opb, proj);
  // 9. final LN + combine
  k_final<<<CB, 256, 0, stream>>>(eo, proj, tki, tkw, ang, anb, out);
  (void)in_sizes; (void)n_in; (void)out_size; (void)ws_size;
}